// Round 7
// baseline (643.018 us; speedup 1.0000x reference)
//
#include <hip/hip_runtime.h>
#include <cstdint>
#include <cstddef>

// Problem constants
#define NB    8192      // batch
#define NP    4849      // params per item
#define PSTR  4864      // padded item stride: 4864*4 = 19456 B (64B-aligned rows)
#define NW    48        // target net width

typedef __attribute__((ext_vector_type(8))) _Float16 f16x8;
typedef __attribute__((ext_vector_type(4))) float f32x4;

// ---------------------------------------------------------------------------
// Parameter layout permutation (unchanged):
// Pp[i*PSTR + rp] = P_orig[i][invperm(rp)], so the Adam kernel (lane j owns
// row j) loads w1/w2 rows with coalesced dwordx4.
// ---------------------------------------------------------------------------
__device__ __forceinline__ int invperm(int rp) {
  if (rp >= 96 && rp < 2400) {
    int t = rp - 96; int kb = t / 192; int rem = t - kb * 192;
    return 96 + (rem >> 2) * 48 + (kb * 4 + (rem & 3));
  }
  if (rp >= 2448 && rp < 4752) {
    int t = rp - 2448; int kb = t / 192; int rem = t - kb * 192;
    return 2448 + (rem >> 2) * 48 + (kb * 4 + (rem & 3));
  }
  return rp;
}

// ---------------------------------------------------------------------------
// Kernel 1: split-fp16 MFMA GEMM, 64(M) x 128(N) tiles, no LDS / no barrier.
//   P[i, rp] = hb2[r] + sum_k H[i,k] * hw2[r,k],  r = invperm(rp)
//   H[i,k] = relu(x_i*hw1[k,0] + c_i*hw1[k,1] + hb1[k])
// R7 changes: (a) ALL 12 B float4 loads hoisted to kernel entry (one L2
// latency exposure instead of 3 serial ones); (b) nontemporal stores for Pp
// (streamed, consumed by next kernel only); (c) launch_bounds(256,4) for
// occupancy (R5 counters: all pipes <30% busy => latency-bound).
// ---------------------------------------------------------------------------
__global__ __launch_bounds__(256, 4) void hyper_gemm(
    const float* __restrict__ x, const float* __restrict__ c,
    const float* __restrict__ hw1, const float* __restrict__ hb1,
    const float* __restrict__ hw2, const float* __restrict__ hb2,
    float* __restrict__ Pp)
{
  const int t   = threadIdx.x;
  const int i0  = blockIdx.y * 64;
  const int rp0 = blockIdx.x * 128;

  const int lane = t & 63;
  const int wv   = t >> 6;
  const int m16  = lane & 15;
  const int q    = lane >> 4;

  // this lane's two B rows (one per n-tile)
  const float* wr[2];
  #pragma unroll
  for (int nt = 0; nt < 2; ++nt) {
    int rp = rp0 + wv * 32 + nt * 16 + m16;
    wr[nt] = hw2 + (size_t)(rp < NP ? invperm(rp) : 0) * 96;
  }

  // ---- hoist ALL B loads (3 chunks x 2 nt x 2 halves) ----
  float4 bfa[3][2][2];
  #pragma unroll
  for (int ch = 0; ch < 3; ++ch) {
    const int k0 = ch * 32 + q * 8;
    #pragma unroll
    for (int nt = 0; nt < 2; ++nt) {
      bfa[ch][nt][0] = *(const float4*)(wr[nt] + k0);
      bfa[ch][nt][1] = *(const float4*)(wr[nt] + k0 + 4);
    }
  }

  // per-lane x/c for the 4 m-tiles
  float xv[4], cv[4];
  #pragma unroll
  for (int mt = 0; mt < 4; ++mt) {
    int i = i0 + mt * 16 + m16;
    xv[mt] = x[i]; cv[mt] = c[i];
  }

  f32x4 acc[4][2];
  #pragma unroll
  for (int mt = 0; mt < 4; ++mt)
    #pragma unroll
    for (int nt = 0; nt < 2; ++nt)
      acc[mt][nt] = (f32x4){0.f, 0.f, 0.f, 0.f};

  #pragma unroll
  for (int ch = 0; ch < 3; ++ch) {
    const int k0 = ch * 32 + q * 8;   // this lane's k-base

    // hw1/hb1 coefficients for k0..k0+7 (quad-uniform, L1-resident)
    float4 A0 = *(const float4*)(hw1 + 2 * k0);
    float4 A1 = *(const float4*)(hw1 + 2 * k0 + 4);
    float4 A2 = *(const float4*)(hw1 + 2 * k0 + 8);
    float4 A3 = *(const float4*)(hw1 + 2 * k0 + 12);
    float4 B0 = *(const float4*)(hb1 + k0);
    float4 B1 = *(const float4*)(hb1 + k0 + 4);
    float w0k[8] = {A0.x,A0.z,A1.x,A1.z,A2.x,A2.z,A3.x,A3.z};
    float w1k[8] = {A0.y,A0.w,A1.y,A1.w,A2.y,A2.w,A3.y,A3.w};
    float bk[8]  = {B0.x,B0.y,B0.z,B0.w,B1.x,B1.y,B1.z,B1.w};

    // A fragments
    f16x8 ah[4], al[4];
    #pragma unroll
    for (int mt = 0; mt < 4; ++mt) {
      #pragma unroll
      for (int j = 0; j < 8; ++j) {
        float h = fmaf(xv[mt], w0k[j], fmaf(cv[mt], w1k[j], bk[j]));
        h = h > 0.f ? h : 0.f;
        _Float16 hi = (_Float16)h;
        float r = h - (float)hi;
        ah[mt][j] = hi;
        al[mt][j] = (_Float16)r;
      }
    }

    // convert B to split-f16 fragments
    f16x8 bh[2], bl[2];
    #pragma unroll
    for (int nt = 0; nt < 2; ++nt) {
      float fv[8] = {bfa[ch][nt][0].x,bfa[ch][nt][0].y,bfa[ch][nt][0].z,bfa[ch][nt][0].w,
                     bfa[ch][nt][1].x,bfa[ch][nt][1].y,bfa[ch][nt][1].z,bfa[ch][nt][1].w};
      #pragma unroll
      for (int e = 0; e < 8; ++e) {
        _Float16 hi = (_Float16)fv[e];
        float r = fv[e] - (float)hi;
        bh[nt][e] = hi;
        bl[nt][e] = (_Float16)r;
      }
    }

    #pragma unroll
    for (int mt = 0; mt < 4; ++mt)
      #pragma unroll
      for (int nt = 0; nt < 2; ++nt) {
        acc[mt][nt] = __builtin_amdgcn_mfma_f32_16x16x32_f16(al[mt], bl[nt], acc[mt][nt], 0, 0, 0);
        acc[mt][nt] = __builtin_amdgcn_mfma_f32_16x16x32_f16(ah[mt], bl[nt], acc[mt][nt], 0, 0, 0);
        acc[mt][nt] = __builtin_amdgcn_mfma_f32_16x16x32_f16(al[mt], bh[nt], acc[mt][nt], 0, 0, 0);
        acc[mt][nt] = __builtin_amdgcn_mfma_f32_16x16x32_f16(ah[mt], bh[nt], acc[mt][nt], 0, 0, 0);
      }
  }

  // ---- epilogue: bias + nontemporal store ----
  #pragma unroll
  for (int nt = 0; nt < 2; ++nt) {
    int rp = rp0 + wv * 32 + nt * 16 + m16;
    if (rp < NP) {
      float bias = hb2[invperm(rp)];
      #pragma unroll
      for (int mt = 0; mt < 4; ++mt)
        #pragma unroll
        for (int r = 0; r < 4; ++r) {
          int i = i0 + mt * 16 + q * 4 + r;
          __builtin_nontemporal_store(acc[mt][nt][r] + bias,
                                      &Pp[(size_t)i * PSTR + rp]);
        }
    }
  }
}

// ---------------------------------------------------------------------------
// Kernel 2: per-item 20-step Adam on g = f'(y).
// R6's LDS-broadcast structure kept (one broadcast ds_read_b128 per 2 k).
// R7 fix: launch_bounds(256,4) — R6's (256,1) collapsed occupancy to 20%
// (1.6 blocks/CU) and left both VALU (58%) and the LDS pipe (~50%) idle:
// latency-bound. VGPR_Count=92 fits 5 waves/SIMD; cap 128 restores ~50% occ.
// ---------------------------------------------------------------------------

// Newton-refined reciprocal: seed ~1 ulp, one NR step -> ~0.5 ulp.
__device__ __forceinline__ float rcp_nr(float d) {
  float r = __builtin_amdgcn_rcpf(d);
  return fmaf(-d, r, 2.f) * r;
}

__global__ __launch_bounds__(256, 4) void adam_inner(
    const float* __restrict__ Pp, float* __restrict__ out)
{
  __shared__ __align__(16) float hd[4][2][128];   // [wave][buf][2*48 used]

  const int lane = threadIdx.x & 63;
  const int wv   = threadIdx.x >> 6;
  const int i    = blockIdx.x * 4 + wv;
  const float* base = Pp + (size_t)i * PSTR;
  const bool act = lane < NW;

  float* buf0 = &hd[wv][0][0];
  float* buf1 = &hd[wv][1][0];

  float w0  = act ? base[lane]        : 0.f;
  float b0  = act ? base[48 + lane]   : 0.f;
  float b1v = act ? base[2400 + lane] : 0.f;
  float b2v = act ? base[4752 + lane] : 0.f;
  float w3  = act ? base[4800 + lane] : 0.f;

  float w1r[48], w2r[48];
  #pragma unroll
  for (int kb = 0; kb < 12; ++kb) {
    float4 q1 = *reinterpret_cast<const float4*>(base + 96 + kb * 192 + lane * 4);
    w1r[4 * kb + 0] = q1.x; w1r[4 * kb + 1] = q1.y;
    w1r[4 * kb + 2] = q1.z; w1r[4 * kb + 3] = q1.w;
    float4 q2 = *reinterpret_cast<const float4*>(base + 2448 + kb * 192 + lane * 4);
    w2r[4 * kb + 0] = q2.x; w2r[4 * kb + 1] = q2.y;
    w2r[4 * kb + 2] = q2.z; w2r[4 * kb + 3] = q2.w;
  }

  float y = 0.f, m = 0.f, v = 0.f;
  float b1t = 1.f, b2t = 1.f;

  #pragma unroll 1
  for (int t = 0; t < 20; ++t) {
    // ---- layer 0 (scalar input): lane j computes unit j ----
    float z  = fmaf(w0, y, b0);
    float e  = fminf(__expf(-z), 8.0e37f);
    float s  = rcp_nr(1.f + e);
    float h  = z * s;
    float dh = fmaf(z * s, 1.f - s, s) * w0;
    if (act) *(float2*)(buf0 + 2 * lane) = make_float2(h, dh);

    // ---- layer 1: z1[j] = b1 + sum_k w1[j,k] h[k]; dz1 likewise ----
    float z1 = b1v, dz1 = 0.f;
    #pragma unroll
    for (int kk = 0; kk < 24; ++kk) {
      float4 p = *(const float4*)(buf0 + 4 * kk);   // h[2kk],dh[2kk],h[2kk+1],dh[2kk+1]
      z1  = fmaf(w1r[2 * kk],     p.x, z1);
      dz1 = fmaf(w1r[2 * kk],     p.y, dz1);
      z1  = fmaf(w1r[2 * kk + 1], p.z, z1);
      dz1 = fmaf(w1r[2 * kk + 1], p.w, dz1);
    }
    e  = fminf(__expf(-z1), 8.0e37f);
    s  = rcp_nr(1.f + e);
    h  = z1 * s;
    dh = fmaf(z1 * s, 1.f - s, s) * dz1;
    if (act) *(float2*)(buf1 + 2 * lane) = make_float2(h, dh);

    // ---- layer 2 ----
    float z2 = b2v, dz2 = 0.f;
    #pragma unroll
    for (int kk = 0; kk < 24; ++kk) {
      float4 p = *(const float4*)(buf1 + 4 * kk);
      z2  = fmaf(w2r[2 * kk],     p.x, z2);
      dz2 = fmaf(w2r[2 * kk],     p.y, dz2);
      z2  = fmaf(w2r[2 * kk + 1], p.z, z2);
      dz2 = fmaf(w2r[2 * kk + 1], p.w, dz2);
    }
    e  = fminf(__expf(-z2), 8.0e37f);
    s  = rcp_nr(1.f + e);
    dh = fmaf(z2 * s, 1.f - s, s) * dz2;

    // ---- g = w3 . dh3 (butterfly reduce) ----
    float tg = act ? w3 * dh : 0.f;
    #pragma unroll
    for (int off = 1; off < 64; off <<= 1) tg += __shfl_xor(tg, off, 64);
    float g = tg;

    // ---- Adam update (replicated per lane) ----
    m = fmaf(0.9f,   m, 0.1f   * g);
    v = fmaf(0.999f, v, 0.001f * g * g);
    b1t *= 0.9f; b2t *= 0.999f;
    float mh  = m * rcp_nr(1.f - b1t);
    float vh  = v * rcp_nr(1.f - b2t);
    float den = __builtin_amdgcn_sqrtf(vh) + 1e-8f;
    y -= 0.1f * mh * rcp_nr(den);
  }

  if (lane == 0) out[i] = y;
}

// ---------------------------------------------------------------------------
extern "C" void kernel_launch(void* const* d_in, const int* in_sizes, int n_in,
                              void* d_out, int out_size, void* d_ws, size_t ws_size,
                              hipStream_t stream) {
  const float* x   = (const float*)d_in[0];
  const float* c   = (const float*)d_in[1];
  const float* hw1 = (const float*)d_in[2];
  const float* hb1 = (const float*)d_in[3];
  const float* hw2 = (const float*)d_in[4];
  const float* hb2 = (const float*)d_in[5];
  float* Pp  = (float*)d_ws;   // NB*PSTR*4 = 159,383,552 bytes
  float* out = (float*)d_out;

  dim3 gridB(38, 128);         // ceil(4849/128) x (8192/64)
  hyper_gemm<<<gridB, dim3(256), 0, stream>>>(x, c, hw1, hb1, hw2, hb2, Pp);
  adam_inner<<<dim3(2048), dim3(256), 0, stream>>>(Pp, out);
}

// Round 8
// 223.678 us; speedup vs baseline: 2.8747x; 2.8747x over previous
//
#include <hip/hip_runtime.h>
#include <cstdint>
#include <cstddef>

// Problem constants
#define NB    8192      // batch
#define NP    4849      // params per item
#define PSTR  4864      // padded item stride: 4864*4 = 19456 B (64B-aligned rows)
#define NW    48        // target net width

typedef __attribute__((ext_vector_type(8))) _Float16 f16x8;
typedef __attribute__((ext_vector_type(4))) float f32x4;
typedef __attribute__((ext_vector_type(2))) float f32x2;

// ---------------------------------------------------------------------------
// Parameter layout permutation (unchanged):
// Pp[i*PSTR + rp] = P_orig[i][invperm(rp)], so the Adam kernel (lane j owns
// row j) loads w1/w2 rows with coalesced dwordx4.
// ---------------------------------------------------------------------------
__device__ __forceinline__ int invperm(int rp) {
  if (rp >= 96 && rp < 2400) {
    int t = rp - 96; int kb = t / 192; int rem = t - kb * 192;
    return 96 + (rem >> 2) * 48 + (kb * 4 + (rem & 3));
  }
  if (rp >= 2448 && rp < 4752) {
    int t = rp - 2448; int kb = t / 192; int rem = t - kb * 192;
    return 2448 + (rem >> 2) * 48 + (kb * 4 + (rem & 3));
  }
  return rp;
}

// ---------------------------------------------------------------------------
// Kernel 1: split-fp16 MFMA GEMM, 64(M) x 128(N), no LDS / no barrier.
// BYTE-EXACT revert to the round-6 version (~105 us measured). R7's triple
// change ((256,4) + hoisted loads + NT stores) was confounded with the adam
// spill disaster; reverting to the known-good baseline.
// ---------------------------------------------------------------------------
__global__ __launch_bounds__(256, 2) void hyper_gemm(
    const float* __restrict__ x, const float* __restrict__ c,
    const float* __restrict__ hw1, const float* __restrict__ hb1,
    const float* __restrict__ hw2, const float* __restrict__ hb2,
    float* __restrict__ Pp)
{
  const int t   = threadIdx.x;
  const int i0  = blockIdx.y * 64;
  const int rp0 = blockIdx.x * 128;

  const int lane = t & 63;
  const int wv   = t >> 6;
  const int m16  = lane & 15;
  const int q    = lane >> 4;

  float xv[4], cv[4];
  #pragma unroll
  for (int mt = 0; mt < 4; ++mt) {
    int i = i0 + mt * 16 + m16;
    xv[mt] = x[i]; cv[mt] = c[i];
  }

  const float* wr[2];
  #pragma unroll
  for (int nt = 0; nt < 2; ++nt) {
    int rp = rp0 + wv * 32 + nt * 16 + m16;
    wr[nt] = hw2 + (size_t)(rp < NP ? invperm(rp) : 0) * 96;
  }

  f32x4 acc[4][2];
  #pragma unroll
  for (int mt = 0; mt < 4; ++mt)
    #pragma unroll
    for (int nt = 0; nt < 2; ++nt)
      acc[mt][nt] = (f32x4){0.f, 0.f, 0.f, 0.f};

  #pragma unroll
  for (int ch = 0; ch < 3; ++ch) {
    const int k0 = ch * 32 + q * 8;

    float4 bf0[2], bf1[2];
    #pragma unroll
    for (int nt = 0; nt < 2; ++nt) {
      bf0[nt] = *(const float4*)(wr[nt] + k0);
      bf1[nt] = *(const float4*)(wr[nt] + k0 + 4);
    }

    float4 A0 = *(const float4*)(hw1 + 2 * k0);
    float4 A1 = *(const float4*)(hw1 + 2 * k0 + 4);
    float4 A2 = *(const float4*)(hw1 + 2 * k0 + 8);
    float4 A3 = *(const float4*)(hw1 + 2 * k0 + 12);
    float4 B0 = *(const float4*)(hb1 + k0);
    float4 B1 = *(const float4*)(hb1 + k0 + 4);
    float w0k[8] = {A0.x,A0.z,A1.x,A1.z,A2.x,A2.z,A3.x,A3.z};
    float w1k[8] = {A0.y,A0.w,A1.y,A1.w,A2.y,A2.w,A3.y,A3.w};
    float bk[8]  = {B0.x,B0.y,B0.z,B0.w,B1.x,B1.y,B1.z,B1.w};

    f16x8 ah[4], al[4];
    #pragma unroll
    for (int mt = 0; mt < 4; ++mt) {
      #pragma unroll
      for (int j = 0; j < 8; ++j) {
        float h = fmaf(xv[mt], w0k[j], fmaf(cv[mt], w1k[j], bk[j]));
        h = h > 0.f ? h : 0.f;
        _Float16 hi = (_Float16)h;
        float r = h - (float)hi;
        ah[mt][j] = hi;
        al[mt][j] = (_Float16)r;
      }
    }

    f16x8 bh[2], bl[2];
    #pragma unroll
    for (int nt = 0; nt < 2; ++nt) {
      float fv[8] = {bf0[nt].x,bf0[nt].y,bf0[nt].z,bf0[nt].w,
                     bf1[nt].x,bf1[nt].y,bf1[nt].z,bf1[nt].w};
      #pragma unroll
      for (int e = 0; e < 8; ++e) {
        _Float16 hi = (_Float16)fv[e];
        float r = fv[e] - (float)hi;
        bh[nt][e] = hi;
        bl[nt][e] = (_Float16)r;
      }
    }

    #pragma unroll
    for (int mt = 0; mt < 4; ++mt)
      #pragma unroll
      for (int nt = 0; nt < 2; ++nt) {
        acc[mt][nt] = __builtin_amdgcn_mfma_f32_16x16x32_f16(al[mt], bl[nt], acc[mt][nt], 0, 0, 0);
        acc[mt][nt] = __builtin_amdgcn_mfma_f32_16x16x32_f16(ah[mt], bl[nt], acc[mt][nt], 0, 0, 0);
        acc[mt][nt] = __builtin_amdgcn_mfma_f32_16x16x32_f16(al[mt], bh[nt], acc[mt][nt], 0, 0, 0);
        acc[mt][nt] = __builtin_amdgcn_mfma_f32_16x16x32_f16(ah[mt], bh[nt], acc[mt][nt], 0, 0, 0);
      }
  }

  #pragma unroll
  for (int nt = 0; nt < 2; ++nt) {
    int rp = rp0 + wv * 32 + nt * 16 + m16;
    if (rp < NP) {
      float bias = hb2[invperm(rp)];
      #pragma unroll
      for (int mt = 0; mt < 4; ++mt)
        #pragma unroll
        for (int r = 0; r < 4; ++r) {
          int i = i0 + mt * 16 + q * 4 + r;
          Pp[(size_t)i * PSTR + rp] = acc[mt][nt][r] + bias;
        }
    }
  }
}

// ---------------------------------------------------------------------------
// Kernel 2: per-item 20-step Adam on g = f'(y).
// R8: (a) launch_bounds back to (256,2) — R7's (256,4) caused scratch spills
// (FETCH 78MB->1.6GB). (b) packed-f32 inner loops: LDS strip de-interleaved
// to h[48]|dh[48]; weights held as f32x2 pairs; even/odd-k partial
// accumulators via __builtin_elementwise_fma on 2-float vectors -> lowers to
// v_pk_fma_f32 (2 MACs/inst), halving the FMA stream and splitting the
// 48-deep dependency chain into 4x depth-12 chains.
// ---------------------------------------------------------------------------

// Newton-refined reciprocal: seed ~1 ulp, one NR step -> ~0.5 ulp.
__device__ __forceinline__ float rcp_nr(float d) {
  float r = __builtin_amdgcn_rcpf(d);
  return fmaf(-d, r, 2.f) * r;
}

__global__ __launch_bounds__(256, 2) void adam_inner(
    const float* __restrict__ Pp, float* __restrict__ out)
{
  __shared__ __align__(16) float hd[4][2][96];   // [wave][buf][h(48)|dh(48)]

  const int lane = threadIdx.x & 63;
  const int wv   = threadIdx.x >> 6;
  const int i    = blockIdx.x * 4 + wv;
  const float* base = Pp + (size_t)i * PSTR;
  const bool act = lane < NW;

  float* buf0 = &hd[wv][0][0];
  float* buf1 = &hd[wv][1][0];

  float w0  = act ? base[lane]        : 0.f;
  float b0  = act ? base[48 + lane]   : 0.f;
  float b1v = act ? base[2400 + lane] : 0.f;
  float b2v = act ? base[4752 + lane] : 0.f;
  float w3  = act ? base[4800 + lane] : 0.f;

  // weights as f32x2 pairs: w1p[2kb]={w[4kb],w[4kb+1]}, w1p[2kb+1]={w[4kb+2],w[4kb+3]}
  f32x2 w1p[24], w2p[24];
  #pragma unroll
  for (int kb = 0; kb < 12; ++kb) {
    float4 q1 = *reinterpret_cast<const float4*>(base + 96 + kb * 192 + lane * 4);
    w1p[2 * kb]     = (f32x2){q1.x, q1.y};
    w1p[2 * kb + 1] = (f32x2){q1.z, q1.w};
    float4 q2 = *reinterpret_cast<const float4*>(base + 2448 + kb * 192 + lane * 4);
    w2p[2 * kb]     = (f32x2){q2.x, q2.y};
    w2p[2 * kb + 1] = (f32x2){q2.z, q2.w};
  }

  float y = 0.f, m = 0.f, v = 0.f;
  float b1t = 1.f, b2t = 1.f;

  #pragma unroll 1
  for (int t = 0; t < 20; ++t) {
    // ---- layer 0 (scalar input): lane j computes unit j ----
    float z  = fmaf(w0, y, b0);
    float e  = fminf(__expf(-z), 8.0e37f);
    float s  = rcp_nr(1.f + e);
    float h  = z * s;
    float dh = fmaf(z * s, 1.f - s, s) * w0;
    if (act) { buf0[lane] = h; buf0[48 + lane] = dh; }

    // ---- layer 1: packed even/odd-k partials ----
    f32x2 zz1a = (f32x2){b1v, 0.f}, zz1b = (f32x2){0.f, 0.f};
    f32x2 dd1a = (f32x2){0.f, 0.f}, dd1b = (f32x2){0.f, 0.f};
    #pragma unroll
    for (int kk = 0; kk < 12; ++kk) {
      float4 ph = *(const float4*)(buf0 + 4 * kk);        // h[4kk..+3] broadcast
      float4 pd = *(const float4*)(buf0 + 48 + 4 * kk);   // dh[4kk..+3]
      zz1a = __builtin_elementwise_fma(w1p[2 * kk],     (f32x2){ph.x, ph.y}, zz1a);
      zz1b = __builtin_elementwise_fma(w1p[2 * kk + 1], (f32x2){ph.z, ph.w}, zz1b);
      dd1a = __builtin_elementwise_fma(w1p[2 * kk],     (f32x2){pd.x, pd.y}, dd1a);
      dd1b = __builtin_elementwise_fma(w1p[2 * kk + 1], (f32x2){pd.z, pd.w}, dd1b);
    }
    float z1  = (zz1a.x + zz1a.y) + (zz1b.x + zz1b.y);
    float dz1 = (dd1a.x + dd1a.y) + (dd1b.x + dd1b.y);

    e  = fminf(__expf(-z1), 8.0e37f);
    s  = rcp_nr(1.f + e);
    h  = z1 * s;
    dh = fmaf(z1 * s, 1.f - s, s) * dz1;
    if (act) { buf1[lane] = h; buf1[48 + lane] = dh; }

    // ---- layer 2 ----
    f32x2 zz2a = (f32x2){b2v, 0.f}, zz2b = (f32x2){0.f, 0.f};
    f32x2 dd2a = (f32x2){0.f, 0.f}, dd2b = (f32x2){0.f, 0.f};
    #pragma unroll
    for (int kk = 0; kk < 12; ++kk) {
      float4 ph = *(const float4*)(buf1 + 4 * kk);
      float4 pd = *(const float4*)(buf1 + 48 + 4 * kk);
      zz2a = __builtin_elementwise_fma(w2p[2 * kk],     (f32x2){ph.x, ph.y}, zz2a);
      zz2b = __builtin_elementwise_fma(w2p[2 * kk + 1], (f32x2){ph.z, ph.w}, zz2b);
      dd2a = __builtin_elementwise_fma(w2p[2 * kk],     (f32x2){pd.x, pd.y}, dd2a);
      dd2b = __builtin_elementwise_fma(w2p[2 * kk + 1], (f32x2){pd.z, pd.w}, dd2b);
    }
    float z2  = (zz2a.x + zz2a.y) + (zz2b.x + zz2b.y);
    float dz2 = (dd2a.x + dd2a.y) + (dd2b.x + dd2b.y);

    e  = fminf(__expf(-z2), 8.0e37f);
    s  = rcp_nr(1.f + e);
    dh = fmaf(z2 * s, 1.f - s, s) * dz2;

    // ---- g = w3 . dh3 (butterfly reduce) ----
    float tg = act ? w3 * dh : 0.f;
    #pragma unroll
    for (int off = 1; off < 64; off <<= 1) tg += __shfl_xor(tg, off, 64);
    float g = tg;

    // ---- Adam update (replicated per lane) ----
    m = fmaf(0.9f,   m, 0.1f   * g);
    v = fmaf(0.999f, v, 0.001f * g * g);
    b1t *= 0.9f; b2t *= 0.999f;
    float mh  = m * rcp_nr(1.f - b1t);
    float vh  = v * rcp_nr(1.f - b2t);
    float den = __builtin_amdgcn_sqrtf(vh) + 1e-8f;
    y -= 0.1f * mh * rcp_nr(den);
  }

  if (lane == 0) out[i] = y;
}

// ---------------------------------------------------------------------------
extern "C" void kernel_launch(void* const* d_in, const int* in_sizes, int n_in,
                              void* d_out, int out_size, void* d_ws, size_t ws_size,
                              hipStream_t stream) {
  const float* x   = (const float*)d_in[0];
  const float* c   = (const float*)d_in[1];
  const float* hw1 = (const float*)d_in[2];
  const float* hb1 = (const float*)d_in[3];
  const float* hw2 = (const float*)d_in[4];
  const float* hb2 = (const float*)d_in[5];
  float* Pp  = (float*)d_ws;   // NB*PSTR*4 = 159,383,552 bytes
  float* out = (float*)d_out;

  dim3 gridB(38, 128);         // ceil(4849/128) x (8192/64)
  hyper_gemm<<<gridB, dim3(256), 0, stream>>>(x, c, hw1, hb1, hw2, hb2, Pp);
  adam_inner<<<dim3(2048), dim3(256), 0, stream>>>(Pp, out);
}